// Round 7
// baseline (2595.117 us; speedup 1.0000x reference)
//
#include <hip/hip_runtime.h>

// ---------------- types / helpers ----------------
typedef __attribute__((ext_vector_type(8))) short bf16x8;
typedef __attribute__((ext_vector_type(4))) float floatx4;
typedef unsigned long long u64;

__device__ __forceinline__ short f2bf(float f) {
  unsigned u = __float_as_uint(f);
  unsigned r = (u + 0x7fffu + ((u >> 16) & 1u)) >> 16;  // RNE
  return (short)r;
}
__device__ __forceinline__ float bf2f(short s) {
  return __uint_as_float(((unsigned)(unsigned short)s) << 16);
}

// ---- transpose + convert: W [K][N] f32 -> Wt [N][K] bf16 ----
__global__ __launch_bounds__(256) void transpose_convert(
    const float* __restrict__ W, short* __restrict__ Wt, int K, int N) {
  __shared__ float tile[32][33];
  const int nt = N >> 5;
  const int bx = blockIdx.x % nt;  // n tile
  const int by = blockIdx.x / nt;  // k tile
  const int tx = threadIdx.x & 31, ty = threadIdx.x >> 5;
#pragma unroll
  for (int i = 0; i < 32; i += 8)
    tile[ty + i][tx] = W[(size_t)(by * 32 + ty + i) * N + bx * 32 + tx];
  __syncthreads();
#pragma unroll
  for (int i = 0; i < 32; i += 8)
    Wt[(size_t)(bx * 32 + ty + i) * K + by * 32 + tx] = f2bf(tile[tx][ty + i]);
}

// ---- convert h0 f32[65536] -> bf16 row 0 of hsb ----
__global__ __launch_bounds__(256) void convert_h0(
    const float* __restrict__ h0, short* __restrict__ dst) {
  const int base = (blockIdx.x * 256 + threadIdx.x) * 4;
#pragma unroll
  for (int j = 0; j < 4; ++j) dst[base + j] = f2bf(h0[base + j]);
}

// ---- generic bf16 MFMA GEMM: C[M][N] = A[M][K] * Bt[N][K]^T + bias ----
template <int A_F32, int OUT_BF16>
__global__ __launch_bounds__(256) void gemm_kernel(
    const void* __restrict__ Aptr, const short* __restrict__ Bt,
    const float* __restrict__ bias, void* __restrict__ Cptr,
    int M, int N, int K) {
  __shared__ short As[128 * 32];
  __shared__ short Bs[128 * 32];
  const int tid = threadIdx.x;
  const int lane = tid & 63;
  const int wv = tid >> 6;
  const int wr = wv >> 1, wc = wv & 1;
  const int nb = N >> 7;
  const int m0 = (blockIdx.x / nb) * 128;
  const int n0 = (blockIdx.x % nb) * 128;
  const int m = lane & 15, q = lane >> 4;
  const int sr = tid >> 1;
  const int sh = (tid & 1) * 16;

  floatx4 acc[4][4];
#pragma unroll
  for (int i = 0; i < 4; ++i)
#pragma unroll
    for (int j = 0; j < 4; ++j) acc[i][j] = (floatx4){0.f, 0.f, 0.f, 0.f};

  for (int kt = 0; kt < K; kt += 32) {
    if (A_F32) {
      const float* A = (const float*)Aptr;
      const float* src = A + (size_t)(m0 + sr) * K + kt + sh;
      const float4 f0 = ((const float4*)src)[0];
      const float4 f1 = ((const float4*)src)[1];
      const float4 f2 = ((const float4*)src)[2];
      const float4 f3 = ((const float4*)src)[3];
      bf16x8 p0, p1;
      p0[0] = f2bf(f0.x); p0[1] = f2bf(f0.y); p0[2] = f2bf(f0.z); p0[3] = f2bf(f0.w);
      p0[4] = f2bf(f1.x); p0[5] = f2bf(f1.y); p0[6] = f2bf(f1.z); p0[7] = f2bf(f1.w);
      p1[0] = f2bf(f2.x); p1[1] = f2bf(f2.y); p1[2] = f2bf(f2.z); p1[3] = f2bf(f2.w);
      p1[4] = f2bf(f3.x); p1[5] = f2bf(f3.y); p1[6] = f2bf(f3.z); p1[7] = f2bf(f3.w);
      *(bf16x8*)&As[sr * 32 + sh] = p0;
      *(bf16x8*)&As[sr * 32 + sh + 8] = p1;
    } else {
      const short* A = (const short*)Aptr;
      const short* src = A + (size_t)(m0 + sr) * K + kt + sh;
      *(bf16x8*)&As[sr * 32 + sh] = *(const bf16x8*)src;
      *(bf16x8*)&As[sr * 32 + sh + 8] = *(const bf16x8*)(src + 8);
    }
    {
      const short* src = Bt + (size_t)(n0 + sr) * K + kt + sh;
      *(bf16x8*)&Bs[sr * 32 + sh] = *(const bf16x8*)src;
      *(bf16x8*)&Bs[sr * 32 + sh + 8] = *(const bf16x8*)(src + 8);
    }
    __syncthreads();
    bf16x8 af[4], bfr[4];
#pragma unroll
    for (int i = 0; i < 4; ++i)
      af[i] = *(bf16x8*)&As[(wr * 64 + i * 16 + m) * 32 + q * 8];
#pragma unroll
    for (int j = 0; j < 4; ++j)
      bfr[j] = *(bf16x8*)&Bs[(wc * 64 + j * 16 + m) * 32 + q * 8];
#pragma unroll
    for (int i = 0; i < 4; ++i)
#pragma unroll
      for (int j = 0; j < 4; ++j)
        acc[i][j] = __builtin_amdgcn_mfma_f32_16x16x32_bf16(af[i], bfr[j], acc[i][j], 0, 0, 0);
    __syncthreads();
  }
#pragma unroll
  for (int i = 0; i < 4; ++i) {
#pragma unroll
    for (int j = 0; j < 4; ++j) {
      const int row0 = m0 + wr * 64 + i * 16 + q * 4;
      const int col = n0 + wc * 64 + j * 16 + m;
      const float bv = bias[col];
#pragma unroll
      for (int r2 = 0; r2 < 4; ++r2) {
        const float v = acc[i][j][r2] + bv;
        if (OUT_BF16)
          ((short*)Cptr)[(size_t)(row0 + r2) * N + col] = f2bf(v);
        else
          ((float*)Cptr)[(size_t)(row0 + r2) * N + col] = v;
      }
    }
  }
}

// ---- persistent scan kernel: flag protocol, per-wave publish, group poll ----
// Round-5 proven chassis: 64 blocks x 256 threads (4 waves), block =
// (bt: 16 batch rows) x (ct: 64 cols); wave w owns n-subtile w with FULL
// K=1024 of W_hh fragments; LDS hin 16B-granule XOR swizzle; producer via
// 2KB LDS tile -> one native 8B agent-scope store per thread.
// Sync changes vs round 5 (both conservative):
//  1) per-wave publish: after the wave's producer stores, inline
//     s_waitcnt vmcnt(0) (per-WAVE counter) + lane0 subflag store
//     flags[block][wave]=t+1. Removes block barrier C and the all-wave
//     drain coupling.
//  2) group-local poll: batch rows are independent chains, so a consumer
//     only needs its bt-group's 16 blocks. Lane i polls subflag
//     (block bt*16+(i>>2), wave i&3) -> 64 cells. Groups skew freely
//     (hsb slots are write-once).
__global__ __launch_bounds__(256, 1) void scan_kernel(
    const short* __restrict__ whh_t, const short* __restrict__ xh,
    short* __restrict__ hsb, float* __restrict__ hfinal,
    unsigned* __restrict__ flags) {
  __shared__ short hin[16 * 1024];
  __shared__ short outb[16 * 64];  // [row 0..15][col 0..63] of this block's tile
  const int tid = threadIdx.x;
  const int lane = tid & 63;
  const int w = tid >> 6;  // wave id == n-subtile
  const int bt = blockIdx.x >> 4;
  const int ct = blockIdx.x & 15;
  const int m = lane & 15, q = lane >> 4;
  const int ncol = ct * 64 + w * 16 + m;

  // W_hh fragments for all 512 steps: full K for this col.
  bf16x8 wf[32];
#pragma unroll
  for (int kk = 0; kk < 32; ++kk)
    wf[kk] = *(const bf16x8*)&whh_t[(size_t)ncol * 1024 + kk * 32 + q * 8];

  // staging: wave w stages rows 4w..4w+3 (lane's row = 4w+q); lane m covers
  // u64 granules m+16*jj. LDS: 16B-granule XOR swizzle (g16 ^ (row&7)).
  const int srow = w * 4 + q;
  const int swz = srow & 7;
  short* hrow_lds = hin + srow * 1024;
  const int xorm = m & 7;
  const short* hinr = hin + m * 1024;

  const size_t growbase = (size_t)(bt * 16 + srow) * 1024;  // shorts, in-slot
  const size_t obase = (size_t)(bt * 16) * 1024 + ncol;     // per-lane out col

  // producer store mapping: thread -> (row, 4-col granule) of the out tile
  const int prow = tid >> 4;
  const int pc4 = (tid & 15) * 4;
  const size_t pdst_off =
      (size_t)(bt * 16 + prow) * 1024 + (size_t)ct * 64 + pc4;  // shorts

  // subflag cells: flags[(block*4 + wave)*32], 128B stride
  unsigned* const mycell = flags + ((size_t)blockIdx.x * 4 + w) * 32;
  // poll mapping: lane i -> block bt*16 + (i>>2), wave i&3 (own group only)
  const unsigned* const pollcell =
      flags + ((size_t)(bt * 16 + (lane >> 2)) * 4 + (lane & 3)) * 32;

  // xh prefetch for t=0
  short xv[4];
#pragma unroll
  for (int i = 0; i < 4; ++i)
    xv[i] = xh[obase + (size_t)(q * 4 + i) * 1024];

  for (int t = 0; t < 512; ++t) {
    // ---- load h(t) rows (agent-scope, flag-guarded by prev iter's poll) ----
    const u64* gp = (const u64*)(hsb + (size_t)t * 65536 + growbase);
    u64 v[16];
#pragma unroll
    for (int jj = 0; jj < 16; ++jj)
      v[jj] = __hip_atomic_load(gp + m + 16 * jj, __ATOMIC_RELAXED,
                                __HIP_MEMORY_SCOPE_AGENT);
    // ---- stage to LDS (swizzled) ----
#pragma unroll
    for (int jj = 0; jj < 16; ++jj) {
      const int k64 = m + 16 * jj;  // u64 index within row (0..255)
      const int g16 = k64 >> 1;     // 16B granule (0..127)
      const int off = ((g16 ^ swz) * 8) + (k64 & 1) * 4;  // shorts
      *(int2*)&hrow_lds[off] = make_int2((int)(unsigned)v[jj], (int)(v[jj] >> 32));
    }
    __syncthreads();  // A: hin ready (and outb of prev step fully consumed)
    // ---- MFMA: 16 rows x 16 cols, K=1024, 4 independent 8-chains ----
    floatx4 acc[4];
#pragma unroll
    for (int c = 0; c < 4; ++c) acc[c] = (floatx4){0.f, 0.f, 0.f, 0.f};
#pragma unroll
    for (int kk = 0; kk < 32; ++kk) {
      const int u = kk * 4 + q;
      const bf16x8 af = *(const bf16x8*)&hinr[(u ^ xorm) * 8];
      acc[kk >> 3] =
          __builtin_amdgcn_mfma_f32_16x16x32_bf16(af, wf[kk], acc[kk >> 3], 0, 0, 0);
    }
    // ---- finish: reduce chunks (round-0 order), tanh -> LDS out tile ----
    const floatx4 sv = (acc[0] + acc[1]) + (acc[2] + acc[3]);
    float yv[4];
#pragma unroll
    for (int i = 0; i < 4; ++i) {
      const float s = sv[i] + bf2f(xv[i]);
      const float e = __expf(2.f * s);
      const float y = 1.f - 2.f / (e + 1.f);
      yv[i] = y;
      outb[(q * 4 + i) * 64 + w * 16 + m] = f2bf(y);
    }
    if (t == 511) {
#pragma unroll
      for (int i = 0; i < 4; ++i)
        hfinal[obase + (size_t)(q * 4 + i) * 1024] = yv[i];
    } else {
      // prefetch next step's xh (consumed next iter; completes under poll)
#pragma unroll
      for (int i = 0; i < 4; ++i)
        xv[i] = xh[(size_t)(t + 1) * 65536 + obase + (size_t)(q * 4 + i) * 1024];
    }
    __syncthreads();  // B: hin reads done AND outb ready
    // ---- producer: one 8B agent-scope store per thread (whole granule) ----
    {
      const u64 ov = *(const u64*)&outb[prow * 64 + pc4];
      __hip_atomic_store((u64*)(hsb + (size_t)(t + 1) * 65536 + pdst_off), ov,
                         __ATOMIC_RELAXED, __HIP_MEMORY_SCOPE_AGENT);
    }
    // ---- per-wave publish: drain THIS wave's stores, lane0 sets subflag ----
    asm volatile("s_waitcnt vmcnt(0)" ::: "memory");
    if (lane == 0)
      __hip_atomic_store(mycell, (unsigned)(t + 1), __ATOMIC_RELAXED,
                         __HIP_MEMORY_SCOPE_AGENT);
    // ---- group-local poll: wait own bt-group's 16 blocks x 4 waves ----
    {
      unsigned spins = 0;
      while (true) {
        const unsigned fv = __hip_atomic_load(pollcell, __ATOMIC_RELAXED,
                                              __HIP_MEMORY_SCOPE_AGENT);
        if (__all((int)(fv > (unsigned)t))) break;
        if (++spins > (1u << 20)) break;  // tripwire: unreachable if correct
        __builtin_amdgcn_s_sleep(1);
      }
    }
  }
}

// ---------------- launcher ----------------
extern "C" void kernel_launch(void* const* d_in, const int* in_sizes, int n_in,
                              void* d_out, int out_size, void* d_ws, size_t ws_size,
                              hipStream_t stream) {
  (void)in_sizes; (void)n_in; (void)out_size; (void)ws_size;
  const float* inputs = (const float*)d_in[0];  // [512,64,512]
  const float* hidden = (const float*)d_in[1];  // [64,1024]
  const float* W_xh = (const float*)d_in[2];    // [512,1024]
  const float* W_hh = (const float*)d_in[3];    // [1024,1024]
  const float* b_h = (const float*)d_in[4];     // [1024]
  const float* W_hq = (const float*)d_in[5];    // [1024,512]
  const float* b_q = (const float*)d_in[6];     // [512]
  float* out = (float*)d_out;

  char* ws = (char*)d_ws;
  size_t o = 0;
  short* xh = (short*)(ws + o);    o += (size_t)512 * 64 * 1024 * 2;
  short* hsb = (short*)(ws + o);   o += (size_t)513 * 64 * 1024 * 2;
  short* wxh_t = (short*)(ws + o); o += (size_t)1024 * 512 * 2;
  short* whh_t = (short*)(ws + o); o += (size_t)1024 * 1024 * 2;
  short* whq_t = (short*)(ws + o); o += (size_t)512 * 1024 * 2;
  unsigned* flags = (unsigned*)(ws + o); o += (size_t)64 * 4 * 32 * 4;
  float* hfinal = out + (size_t)32768 * 512;

  hipMemsetAsync(flags, 0, (size_t)64 * 4 * 32 * 4, stream);
  transpose_convert<<<dim3((512 / 32) * (1024 / 32)), dim3(256), 0, stream>>>(W_xh, wxh_t, 512, 1024);
  transpose_convert<<<dim3((1024 / 32) * (1024 / 32)), dim3(256), 0, stream>>>(W_hh, whh_t, 1024, 1024);
  transpose_convert<<<dim3((1024 / 32) * (512 / 32)), dim3(256), 0, stream>>>(W_hq, whq_t, 1024, 512);
  convert_h0<<<dim3(64), dim3(256), 0, stream>>>(hidden, hsb);

  gemm_kernel<1, 1><<<dim3((32768 / 128) * (1024 / 128)), dim3(256), 0, stream>>>(
      (const void*)inputs, wxh_t, b_h, (void*)xh, 32768, 1024, 512);

  {
    void* kargs[5];
    kargs[0] = (void*)&whh_t;
    kargs[1] = (void*)&xh;
    kargs[2] = (void*)&hsb;
    kargs[3] = (void*)&hfinal;
    kargs[4] = (void*)&flags;
    hipLaunchCooperativeKernel((const void*)scan_kernel, dim3(64), dim3(256), kargs, 0, stream);
  }

  gemm_kernel<0, 0><<<dim3((32768 / 128) * (512 / 128)), dim3(256), 0, stream>>>(
      (const void*)(hsb + 65536), whq_t, b_q, (void*)out, 32768, 512, 1024);
}

// Round 9
// 1499.915 us; speedup vs baseline: 1.7302x; 1.7302x over previous
//
#include <hip/hip_runtime.h>

// ---------------- types / helpers ----------------
typedef __attribute__((ext_vector_type(8))) short bf16x8;
typedef __attribute__((ext_vector_type(4))) float floatx4;
typedef unsigned long long u64;

__device__ __forceinline__ short f2bf(float f) {
  unsigned u = __float_as_uint(f);
  unsigned r = (u + 0x7fffu + ((u >> 16) & 1u)) >> 16;  // RNE
  return (short)r;
}
__device__ __forceinline__ float bf2f(short s) {
  return __uint_as_float(((unsigned)(unsigned short)s) << 16);
}

// ---- transpose + convert: W [K][N] f32 -> Wt [N][K] bf16 ----
__global__ __launch_bounds__(256) void transpose_convert(
    const float* __restrict__ W, short* __restrict__ Wt, int K, int N) {
  __shared__ float tile[32][33];
  const int nt = N >> 5;
  const int bx = blockIdx.x % nt;  // n tile
  const int by = blockIdx.x / nt;  // k tile
  const int tx = threadIdx.x & 31, ty = threadIdx.x >> 5;
#pragma unroll
  for (int i = 0; i < 32; i += 8)
    tile[ty + i][tx] = W[(size_t)(by * 32 + ty + i) * N + bx * 32 + tx];
  __syncthreads();
#pragma unroll
  for (int i = 0; i < 32; i += 8)
    Wt[(size_t)(bx * 32 + ty + i) * K + by * 32 + tx] = f2bf(tile[tx][ty + i]);
}

// ---- convert h0 f32[65536] -> bf16 row 0 of hsb ----
__global__ __launch_bounds__(256) void convert_h0(
    const float* __restrict__ h0, short* __restrict__ dst) {
  const int base = (blockIdx.x * 256 + threadIdx.x) * 4;
#pragma unroll
  for (int j = 0; j < 4; ++j) dst[base + j] = f2bf(h0[base + j]);
}

// ---- generic bf16 MFMA GEMM: C[M][N] = A[M][K] * Bt[N][K]^T + bias ----
template <int A_F32, int OUT_BF16>
__global__ __launch_bounds__(256) void gemm_kernel(
    const void* __restrict__ Aptr, const short* __restrict__ Bt,
    const float* __restrict__ bias, void* __restrict__ Cptr,
    int M, int N, int K) {
  __shared__ short As[128 * 32];
  __shared__ short Bs[128 * 32];
  const int tid = threadIdx.x;
  const int lane = tid & 63;
  const int wv = tid >> 6;
  const int wr = wv >> 1, wc = wv & 1;
  const int nb = N >> 7;
  const int m0 = (blockIdx.x / nb) * 128;
  const int n0 = (blockIdx.x % nb) * 128;
  const int m = lane & 15, q = lane >> 4;
  const int sr = tid >> 1;
  const int sh = (tid & 1) * 16;

  floatx4 acc[4][4];
#pragma unroll
  for (int i = 0; i < 4; ++i)
#pragma unroll
    for (int j = 0; j < 4; ++j) acc[i][j] = (floatx4){0.f, 0.f, 0.f, 0.f};

  for (int kt = 0; kt < K; kt += 32) {
    if (A_F32) {
      const float* A = (const float*)Aptr;
      const float* src = A + (size_t)(m0 + sr) * K + kt + sh;
      const float4 f0 = ((const float4*)src)[0];
      const float4 f1 = ((const float4*)src)[1];
      const float4 f2 = ((const float4*)src)[2];
      const float4 f3 = ((const float4*)src)[3];
      bf16x8 p0, p1;
      p0[0] = f2bf(f0.x); p0[1] = f2bf(f0.y); p0[2] = f2bf(f0.z); p0[3] = f2bf(f0.w);
      p0[4] = f2bf(f1.x); p0[5] = f2bf(f1.y); p0[6] = f2bf(f1.z); p0[7] = f2bf(f1.w);
      p1[0] = f2bf(f2.x); p1[1] = f2bf(f2.y); p1[2] = f2bf(f2.z); p1[3] = f2bf(f2.w);
      p1[4] = f2bf(f3.x); p1[5] = f2bf(f3.y); p1[6] = f2bf(f3.z); p1[7] = f2bf(f3.w);
      *(bf16x8*)&As[sr * 32 + sh] = p0;
      *(bf16x8*)&As[sr * 32 + sh + 8] = p1;
    } else {
      const short* A = (const short*)Aptr;
      const short* src = A + (size_t)(m0 + sr) * K + kt + sh;
      *(bf16x8*)&As[sr * 32 + sh] = *(const bf16x8*)src;
      *(bf16x8*)&As[sr * 32 + sh + 8] = *(const bf16x8*)(src + 8);
    }
    {
      const short* src = Bt + (size_t)(n0 + sr) * K + kt + sh;
      *(bf16x8*)&Bs[sr * 32 + sh] = *(const bf16x8*)src;
      *(bf16x8*)&Bs[sr * 32 + sh + 8] = *(const bf16x8*)(src + 8);
    }
    __syncthreads();
    bf16x8 af[4], bfr[4];
#pragma unroll
    for (int i = 0; i < 4; ++i)
      af[i] = *(bf16x8*)&As[(wr * 64 + i * 16 + m) * 32 + q * 8];
#pragma unroll
    for (int j = 0; j < 4; ++j)
      bfr[j] = *(bf16x8*)&Bs[(wc * 64 + j * 16 + m) * 32 + q * 8];
#pragma unroll
    for (int i = 0; i < 4; ++i)
#pragma unroll
      for (int j = 0; j < 4; ++j)
        acc[i][j] = __builtin_amdgcn_mfma_f32_16x16x32_bf16(af[i], bfr[j], acc[i][j], 0, 0, 0);
    __syncthreads();
  }
#pragma unroll
  for (int i = 0; i < 4; ++i) {
#pragma unroll
    for (int j = 0; j < 4; ++j) {
      const int row0 = m0 + wr * 64 + i * 16 + q * 4;
      const int col = n0 + wc * 64 + j * 16 + m;
      const float bv = bias[col];
#pragma unroll
      for (int r2 = 0; r2 < 4; ++r2) {
        const float v = acc[i][j][r2] + bv;
        if (OUT_BF16)
          ((short*)Cptr)[(size_t)(row0 + r2) * N + col] = f2bf(v);
        else
          ((float*)Cptr)[(size_t)(row0 + r2) * N + col] = v;
      }
    }
  }
}

// ---- persistent scan kernel: r5 protocol + 3 safe deltas ----
// Chassis identical to the PASSING round-5 kernel: 64 blocks x 256 threads
// (4 waves), block = (bt: 16 batch rows) x (ct: 64 cols); wave w owns
// n-subtile w with FULL K=1024 of W_hh in 128 VGPRs; LDS hin 16B-granule
// XOR swizzle; producer via 2KB LDS tile -> one native 8B agent-scope store
// per thread; store -> barrier C (vmcnt drain) -> single tid0 flag store ->
// full poll -> ONLY THEN bulk data loads (next iter). Deltas vs r5:
//  1) xh(t+1) prefetch moved AFTER barrier C + flag store: __syncthreads
//     drains vmcnt (loads too), so r5's before-B placement stalled barrier B
//     on an LLC load. Now it genuinely overlaps the poll.
//  2) group-local poll: lane polls flag of own-group block bt*16+(lane&15)
//     (r7 proved group skew safe; bulk-load-after-full-poll preserved).
//  3) t=511: no flag, no poll (slot 512 is read only by the post-scan GEMM).
__global__ __launch_bounds__(256, 1) void scan_kernel(
    const short* __restrict__ whh_t, const short* __restrict__ xh,
    short* __restrict__ hsb, float* __restrict__ hfinal,
    unsigned* __restrict__ flags) {
  __shared__ short hin[16 * 1024];
  __shared__ short outb[16 * 64];  // [row 0..15][col 0..63] of this block's tile
  const int tid = threadIdx.x;
  const int lane = tid & 63;
  const int w = tid >> 6;  // wave id == n-subtile
  const int bt = blockIdx.x >> 4;
  const int ct = blockIdx.x & 15;
  const int m = lane & 15, q = lane >> 4;
  const int ncol = ct * 64 + w * 16 + m;

  // W_hh fragments for all 512 steps: full K for this col.
  bf16x8 wf[32];
#pragma unroll
  for (int kk = 0; kk < 32; ++kk)
    wf[kk] = *(const bf16x8*)&whh_t[(size_t)ncol * 1024 + kk * 32 + q * 8];

  // staging: wave w stages rows 4w..4w+3 (lane's row = 4w+q); lane m covers
  // u64 granules m+16*jj. LDS: 16B-granule XOR swizzle (g16 ^ (row&7)).
  const int srow = w * 4 + q;
  const int swz = srow & 7;
  short* hrow_lds = hin + srow * 1024;
  const int xorm = m & 7;
  const short* hinr = hin + m * 1024;

  const size_t growbase = (size_t)(bt * 16 + srow) * 1024;  // shorts, in-slot
  const size_t obase = (size_t)(bt * 16) * 1024 + ncol;     // per-lane out col

  // producer store mapping: thread -> (row, 4-col granule) of the out tile
  const int prow = tid >> 4;
  const int pc4 = (tid & 15) * 4;
  const size_t pdst_off =
      (size_t)(bt * 16 + prow) * 1024 + (size_t)ct * 64 + pc4;  // shorts

  unsigned* const myflag = flags + blockIdx.x * 32;  // 128B stride
  // group-local poll: lane i -> flag of own-group block bt*16 + (i&15)
  const unsigned* const fp = flags + (size_t)(bt * 16 + (lane & 15)) * 32;

  // xh prefetch for t=0
  short xv[4];
#pragma unroll
  for (int i = 0; i < 4; ++i)
    xv[i] = xh[obase + (size_t)(q * 4 + i) * 1024];

  for (int t = 0; t < 512; ++t) {
    // ---- load h(t) rows (agent-scope; gated by prev iter's FULL poll) ----
    const u64* gp = (const u64*)(hsb + (size_t)t * 65536 + growbase);
    u64 v[16];
#pragma unroll
    for (int jj = 0; jj < 16; ++jj)
      v[jj] = __hip_atomic_load(gp + m + 16 * jj, __ATOMIC_RELAXED,
                                __HIP_MEMORY_SCOPE_AGENT);
    // ---- stage to LDS (swizzled) ----
#pragma unroll
    for (int jj = 0; jj < 16; ++jj) {
      const int k64 = m + 16 * jj;  // u64 index within row (0..255)
      const int g16 = k64 >> 1;     // 16B granule (0..127)
      const int off = ((g16 ^ swz) * 8) + (k64 & 1) * 4;  // shorts
      *(int2*)&hrow_lds[off] = make_int2((int)(unsigned)v[jj], (int)(v[jj] >> 32));
    }
    __syncthreads();  // A: hin ready (and outb of prev step fully consumed)
    // ---- MFMA: 16 rows x 16 cols, K=1024, 4 independent 8-chains ----
    floatx4 acc[4];
#pragma unroll
    for (int c = 0; c < 4; ++c) acc[c] = (floatx4){0.f, 0.f, 0.f, 0.f};
#pragma unroll
    for (int kk = 0; kk < 32; ++kk) {
      const int u = kk * 4 + q;
      const bf16x8 af = *(const bf16x8*)&hinr[(u ^ xorm) * 8];
      acc[kk >> 3] =
          __builtin_amdgcn_mfma_f32_16x16x32_bf16(af, wf[kk], acc[kk >> 3], 0, 0, 0);
    }
    // ---- finish: reduce chunks (round-0 order), tanh -> LDS out tile ----
    const floatx4 sv = (acc[0] + acc[1]) + (acc[2] + acc[3]);
    float yv[4];
#pragma unroll
    for (int i = 0; i < 4; ++i) {
      const float s = sv[i] + bf2f(xv[i]);
      const float e = __expf(2.f * s);
      const float y = 1.f - 2.f / (e + 1.f);
      yv[i] = y;
      outb[(q * 4 + i) * 64 + w * 16 + m] = f2bf(y);
    }
    if (t == 511) {
#pragma unroll
      for (int i = 0; i < 4; ++i)
        hfinal[obase + (size_t)(q * 4 + i) * 1024] = yv[i];
    }
    __syncthreads();  // B: hin reads done AND outb ready (no loads pending)
    // ---- producer: one 8B agent-scope store per thread (whole granule) ----
    {
      const u64 ov = *(const u64*)&outb[prow * 64 + pc4];
      __hip_atomic_store((u64*)(hsb + (size_t)(t + 1) * 65536 + pdst_off), ov,
                         __ATOMIC_RELAXED, __HIP_MEMORY_SCOPE_AGENT);
    }
    __syncthreads();  // C: data stores drained (vmcnt0 before barrier)
    if (t < 511) {
      if (tid == 0)
        __hip_atomic_store(myflag, (unsigned)(t + 1), __ATOMIC_RELAXED,
                           __HIP_MEMORY_SCOPE_AGENT);
      // xh prefetch for t+1: issued after C, completes under the poll
#pragma unroll
      for (int i = 0; i < 4; ++i)
        xv[i] = xh[(size_t)(t + 1) * 65536 + obase + (size_t)(q * 4 + i) * 1024];
      // ---- full group-local poll; bulk loads happen only next iter ----
      unsigned spins = 0;
      while (true) {
        const unsigned fv = __hip_atomic_load(fp, __ATOMIC_RELAXED,
                                              __HIP_MEMORY_SCOPE_AGENT);
        if (__all((int)(fv > (unsigned)t))) break;
        if (++spins > (1u << 20)) break;  // tripwire: unreachable if correct
        __builtin_amdgcn_s_sleep(1);
      }
    }
  }
}

// ---------------- launcher ----------------
extern "C" void kernel_launch(void* const* d_in, const int* in_sizes, int n_in,
                              void* d_out, int out_size, void* d_ws, size_t ws_size,
                              hipStream_t stream) {
  (void)in_sizes; (void)n_in; (void)out_size; (void)ws_size;
  const float* inputs = (const float*)d_in[0];  // [512,64,512]
  const float* hidden = (const float*)d_in[1];  // [64,1024]
  const float* W_xh = (const float*)d_in[2];    // [512,1024]
  const float* W_hh = (const float*)d_in[3];    // [1024,1024]
  const float* b_h = (const float*)d_in[4];     // [1024]
  const float* W_hq = (const float*)d_in[5];    // [1024,512]
  const float* b_q = (const float*)d_in[6];     // [512]
  float* out = (float*)d_out;

  char* ws = (char*)d_ws;
  size_t o = 0;
  short* xh = (short*)(ws + o);    o += (size_t)512 * 64 * 1024 * 2;
  short* hsb = (short*)(ws + o);   o += (size_t)513 * 64 * 1024 * 2;
  short* wxh_t = (short*)(ws + o); o += (size_t)1024 * 512 * 2;
  short* whh_t = (short*)(ws + o); o += (size_t)1024 * 1024 * 2;
  short* whq_t = (short*)(ws + o); o += (size_t)512 * 1024 * 2;
  unsigned* flags = (unsigned*)(ws + o); o += 64 * 32 * 4;
  float* hfinal = out + (size_t)32768 * 512;

  hipMemsetAsync(flags, 0, 64 * 32 * 4, stream);
  transpose_convert<<<dim3((512 / 32) * (1024 / 32)), dim3(256), 0, stream>>>(W_xh, wxh_t, 512, 1024);
  transpose_convert<<<dim3((1024 / 32) * (1024 / 32)), dim3(256), 0, stream>>>(W_hh, whh_t, 1024, 1024);
  transpose_convert<<<dim3((1024 / 32) * (512 / 32)), dim3(256), 0, stream>>>(W_hq, whq_t, 1024, 512);
  convert_h0<<<dim3(64), dim3(256), 0, stream>>>(hidden, hsb);

  gemm_kernel<1, 1><<<dim3((32768 / 128) * (1024 / 128)), dim3(256), 0, stream>>>(
      (const void*)inputs, wxh_t, b_h, (void*)xh, 32768, 1024, 512);

  {
    void* kargs[5];
    kargs[0] = (void*)&whh_t;
    kargs[1] = (void*)&xh;
    kargs[2] = (void*)&hsb;
    kargs[3] = (void*)&hfinal;
    kargs[4] = (void*)&flags;
    hipLaunchCooperativeKernel((const void*)scan_kernel, dim3(64), dim3(256), kargs, 0, stream);
  }

  gemm_kernel<0, 0><<<dim3((32768 / 128) * (512 / 128)), dim3(256), 0, stream>>>(
      (const void*)(hsb + 65536), whq_t, b_q, (void*)out, 32768, 512, 1024);
}